// Round 12
// baseline (221.410 us; speedup 1.0000x reference)
//
#include <hip/hip_runtime.h>

#define BATCH 4
#define SLEN 2048
#define DMODEL 1024
#define NHEADS 16
#define DK 64
#define MROWS (BATCH * SLEN)  // 8192
#define NQB 16                // SLEN/128 q-strips
#define SCALE_LOG2E 0.1803368801111731f  // 0.125 * log2(e), folded into Q

typedef short bf16x8 __attribute__((ext_vector_type(8)));
typedef unsigned short u16x4 __attribute__((ext_vector_type(4)));
typedef float f32x4 __attribute__((ext_vector_type(4)));

__device__ __forceinline__ unsigned short f2bf(float f) {
    unsigned u = __float_as_uint(f);
    unsigned r = u + 0x7FFFu + ((u >> 16) & 1u);
    return (unsigned short)(r >> 16);
}

// packed f32x2 -> bf16x2 (single HW instr; no builtin on gfx950)
__device__ __forceinline__ unsigned pkbf(float a, float b) {
    unsigned r;
    asm volatile("v_cvt_pk_bf16_f32 %0, %1, %2" : "=v"(r) : "v"(a), "v"(b));
    return r;
}

__device__ __forceinline__ void gload_lds16(const void* g, void* l) {
    __builtin_amdgcn_global_load_lds(
        (const __attribute__((address_space(1))) void*)g,
        (__attribute__((address_space(3))) void*)l, 16, 0, 0);
}

__global__ void cvt_f32_bf16(const float* __restrict__ in, unsigned short* __restrict__ out, int n) {
    int i = (blockIdx.x * blockDim.x + threadIdx.x) * 4;
    if (i >= n) return;
    float4 v = *reinterpret_cast<const float4*>(in + i);
    u16x4 o;
    o[0] = f2bf(v.x); o[1] = f2bf(v.y); o[2] = f2bf(v.z); o[3] = f2bf(v.w);
    *reinterpret_cast<u16x4*>(out + i) = o;
}

__global__ void cvt_w_all(const float* __restrict__ w0, const float* __restrict__ w1,
                          const float* __restrict__ w2, const float* __restrict__ w3,
                          unsigned short* __restrict__ o0, unsigned short* __restrict__ o1,
                          unsigned short* __restrict__ o2, unsigned short* __restrict__ o3) {
    int z = blockIdx.y;
    const float* src = (z == 0) ? w0 : (z == 1) ? w1 : (z == 2) ? w2 : w3;
    unsigned short* dst = (z == 0) ? o0 : (z == 1) ? o1 : (z == 2) ? o2 : o3;
    int i = (blockIdx.x * blockDim.x + threadIdx.x) * 4;
    float4 v = *reinterpret_cast<const float4*>(src + i);
    u16x4 o;
    o[0] = f2bf(v.x); o[1] = f2bf(v.y); o[2] = f2bf(v.z); o[3] = f2bf(v.w);
    *reinterpret_cast<u16x4*>(dst + i) = o;
}

__global__ void rope_table(const int* __restrict__ tok, float* __restrict__ cs, float* __restrict__ sn) {
    int idx = blockIdx.x * blockDim.x + threadIdx.x;
    if (idx >= SLEN * 32) return;
    int s = idx >> 5, fi = idx & 31;
    float invf = powf(10000.0f, -(float)(2 * fi) / 64.0f);
    float ang = (float)tok[s] * invf;
    cs[idx] = cosf(ang);
    sn[idx] = sinf(ang);
}

// ======= qkv FUSED: one block computes a 128(M) x 64(N) tile for ALL THREE
// projections. X tile staged ONCE per K-step, reused by 3 z's: 48 MFMA per
// 10-load drain vs 32 per 8 (R5). 1024 blocks vs 1536 -> fewer drain
// serializations. R5-proven single-buffer drain semantics, R5 swizzle. =======
__global__ __launch_bounds__(256) void qkv_gemm(
    const unsigned short* __restrict__ X,
    const unsigned short* __restrict__ Wq,
    const unsigned short* __restrict__ Wk,
    const unsigned short* __restrict__ Wv,
    const float* __restrict__ cs_tab, const float* __restrict__ sn_tab,
    unsigned short* __restrict__ Q, unsigned short* __restrict__ K,
    unsigned short* __restrict__ VT)
{
    __shared__ alignas(16) unsigned short As[128 * 64];      // 16 KB
    __shared__ alignas(16) unsigned short Bs[3][64 * 64];    // 24 KB
    const int tid = threadIdx.x, lane = tid & 63, wave = tid >> 6;
    const int ln = lane & 15, kq = lane >> 4;
    const int wr = wave >> 1, wc = wave & 1;   // wave tile: 64 x 32 (per z)
    const int m0 = blockIdx.x * 128;
    const int n0 = blockIdx.y * 64;
    const unsigned short* Ws[3] = {Wq, Wk, Wv};

    f32x4 acc[3][4][2];
#pragma unroll
    for (int z = 0; z < 3; z++)
#pragma unroll
        for (int a = 0; a < 4; a++)
#pragma unroll
            for (int b = 0; b < 2; b++) acc[z][a][b] = (f32x4){0.f, 0.f, 0.f, 0.f};

    for (int k0 = 0; k0 < DMODEL; k0 += 64) {
        if (k0) __syncthreads();
        // stage A: 128x64 (1024 slots of 16B, 4/thread), R5 swizzle
#pragma unroll
        for (int i = 0; i < 4; i++) {
            int s = i * 256 + tid;
            int r = s >> 3;
            int u = (s & 7) ^ (r & 7);
            gload_lds16(X + (size_t)(m0 + r) * DMODEL + k0 + u * 8, &As[(i * 256 + wave * 64) * 8]);
        }
        // stage B[z]: 64x64 each (512 slots, 2/thread per z)
#pragma unroll
        for (int z = 0; z < 3; z++)
#pragma unroll
            for (int i = 0; i < 2; i++) {
                int s = i * 256 + tid;
                int r = s >> 3;
                int u = (s & 7) ^ (r & 7);
                gload_lds16(Ws[z] + (size_t)(n0 + r) * DMODEL + k0 + u * 8,
                            &Bs[z][(i * 256 + wave * 64) * 8]);
            }
        __syncthreads();

        bf16x8 af[4][2];
#pragma unroll
        for (int mt = 0; mt < 4; mt++) {
            int row = wr * 64 + mt * 16 + ln;
#pragma unroll
            for (int kc = 0; kc < 2; kc++) {
                int u = (kc * 4 + kq) ^ (row & 7);
                af[mt][kc] = *reinterpret_cast<const bf16x8*>(&As[row * 64 + u * 8]);
            }
        }
#pragma unroll
        for (int z = 0; z < 3; z++) {
            bf16x8 bfr[2][2];
#pragma unroll
            for (int nt = 0; nt < 2; nt++) {
                int row = wc * 32 + nt * 16 + ln;
#pragma unroll
                for (int kc = 0; kc < 2; kc++) {
                    int u = (kc * 4 + kq) ^ (row & 7);
                    bfr[nt][kc] = *reinterpret_cast<const bf16x8*>(&Bs[z][row * 64 + u * 8]);
                }
            }
            __builtin_amdgcn_s_setprio(1);
#pragma unroll
            for (int kc = 0; kc < 2; kc++)
#pragma unroll
                for (int mt = 0; mt < 4; mt++)
#pragma unroll
                    for (int nt = 0; nt < 2; nt++)
                        acc[z][mt][nt] = __builtin_amdgcn_mfma_f32_16x16x32_bf16(
                            af[mt][kc], bfr[nt][kc], acc[z][mt][nt], 0, 0, 0);
            __builtin_amdgcn_s_setprio(0);
        }
    }

    // ---- epilogue: RoPE for Q/K, transpose-scatter for V ----
    int m0w = m0 + wr * 64;
    int n0w = n0 + wc * 32;
#pragma unroll
    for (int z = 0; z < 2; z++) {
        unsigned short* dst = z ? K : Q;
#pragma unroll
        for (int nt = 0; nt < 2; nt++) {
            int n = n0w + nt * 16 + ln;
            int h = n >> 6, d = n & 63;
            int fi = d >> 1;
#pragma unroll
            for (int mt = 0; mt < 4; mt++) {
#pragma unroll
                for (int j = 0; j < 4; j++) {
                    int m = m0w + mt * 16 + kq * 4 + j;
                    int b = m >> 11, s = m & (SLEN - 1);
                    float v = acc[z][mt][nt][j];
                    float c = cs_tab[s * 32 + fi];
                    float si = sn_tab[s * 32 + fi];
                    float p = __shfl_xor(v, 1);
                    v = (d & 1) ? (p * si + v * c) : (v * c - p * si);
                    if (z == 0) v *= SCALE_LOG2E;
                    dst[(((size_t)(b * NHEADS + h) * SLEN + s) << 6) + d] = f2bf(v);
                }
            }
        }
    }
#pragma unroll
    for (int nt = 0; nt < 2; nt++) {
        int n = n0w + nt * 16 + ln;
        int h = n >> 6, d = n & 63;
#pragma unroll
        for (int mt = 0; mt < 4; mt++) {
#pragma unroll
            for (int j = 0; j < 4; j++) {
                int m = m0w + mt * 16 + kq * 4 + j;
                int b = m >> 11, s = m & (SLEN - 1);
                VT[((size_t)(b * NHEADS + h) * DK + d) * SLEN + s] = f2bf(acc[2][mt][nt][j]);
            }
        }
    }
}

// ---- single-buffered 128x128 GEMM core (R5-verified, BK=64) ----
__device__ __forceinline__ void gemm128_core_sb(
    const unsigned short* __restrict__ A, const unsigned short* __restrict__ B,
    int m0, int n0, int tid, f32x4 (&acc)[4][4],
    unsigned short* As, unsigned short* Bs)
{
    int lane = tid & 63, wave = tid >> 6;
    int ln = lane & 15, kq = lane >> 4;
    int wr = wave >> 1, wc = wave & 1;
#pragma unroll
    for (int a = 0; a < 4; a++)
#pragma unroll
        for (int b = 0; b < 4; b++) acc[a][b] = (f32x4){0.f, 0.f, 0.f, 0.f};

    for (int k0 = 0; k0 < DMODEL; k0 += 64) {
        if (k0) __syncthreads();
#pragma unroll
        for (int i = 0; i < 4; i++) {
            int s = i * 256 + tid;
            int r = s >> 3;
            int u = (s & 7) ^ (r & 7);
            gload_lds16(A + (size_t)(m0 + r) * DMODEL + k0 + u * 8, &As[(i * 256 + wave * 64) * 8]);
            gload_lds16(B + (size_t)(n0 + r) * DMODEL + k0 + u * 8, &Bs[(i * 256 + wave * 64) * 8]);
        }
        __syncthreads();

        bf16x8 af[4][2], bfr[4][2];
#pragma unroll
        for (int mt = 0; mt < 4; mt++) {
            int row = wr * 64 + mt * 16 + ln;
#pragma unroll
            for (int kc = 0; kc < 2; kc++) {
                int u = (kc * 4 + kq) ^ (row & 7);
                af[mt][kc] = *reinterpret_cast<const bf16x8*>(&As[row * 64 + u * 8]);
            }
        }
#pragma unroll
        for (int nt = 0; nt < 4; nt++) {
            int row = wc * 64 + nt * 16 + ln;
#pragma unroll
            for (int kc = 0; kc < 2; kc++) {
                int u = (kc * 4 + kq) ^ (row & 7);
                bfr[nt][kc] = *reinterpret_cast<const bf16x8*>(&Bs[row * 64 + u * 8]);
            }
        }
        __builtin_amdgcn_s_setprio(1);
#pragma unroll
        for (int kc = 0; kc < 2; kc++)
#pragma unroll
            for (int mt = 0; mt < 4; mt++)
#pragma unroll
                for (int nt = 0; nt < 4; nt++)
                    acc[mt][nt] = __builtin_amdgcn_mfma_f32_16x16x32_bf16(af[mt][kc], bfr[nt][kc], acc[mt][nt], 0, 0, 0);
        __builtin_amdgcn_s_setprio(0);
    }
}

// ---- Causal flash attention v5 (R5-verified): pi-permuted K, P in-register ----
__global__ __launch_bounds__(256, 4) void attn_kernel(
    const unsigned short* __restrict__ Q, const unsigned short* __restrict__ K,
    const unsigned short* __restrict__ VT, unsigned short* __restrict__ O)
{
    __shared__ alignas(16) unsigned short Kt[2][4096];
    __shared__ alignas(16) unsigned short Vt[2][4096];

    int tid = threadIdx.x, lane = tid & 63, wave = tid >> 6;
    int ln = lane & 15, kq = lane >> 4;
    int qb = blockIdx.x;  // 0..7
    int h = blockIdx.y, b = blockIdx.z;
    size_t headoff = ((size_t)b * NHEADS + h) * SLEN * DK;
    const unsigned short* Qh = Q + headoff;
    const unsigned short* Kh = K + headoff;
    const unsigned short* Vh = VT + headoff;  // [64][SLEN]

    auto stage = [&](int buf, int t) {
        int kv0 = t << 6;
#pragma unroll
        for (int i = 0; i < 2; i++) {
            int s = i * 256 + tid;
            int r = s >> 3;
            int cb = (s & 7) ^ (r & 7);
            int rp = ((r >> 5) << 5) | (((r >> 2) & 3) << 3) | (((r >> 4) & 1) << 2) | (r & 3);
            gload_lds16(Kh + (size_t)(kv0 + rp) * DK + cb * 8,
                        &Kt[buf][(i * 256 + wave * 64) * 8]);
            gload_lds16(Vh + (size_t)r * SLEN + kv0 + cb * 8,
                        &Vt[buf][(i * 256 + wave * 64) * 8]);
        }
    };

    for (int sid = 0; sid < 2; sid++) {
        int qs = sid ? qb : (NQB - 1 - qb);
        int q0 = qs * 128 + wave * 32;

        bf16x8 aq[2][2];
#pragma unroll
        for (int mt = 0; mt < 2; mt++)
#pragma unroll
            for (int kc = 0; kc < 2; kc++)
                aq[mt][kc] = *reinterpret_cast<const bf16x8*>(
                    Qh + (size_t)(q0 + mt * 16 + ln) * DK + kc * 32 + kq * 8);

        f32x4 oacc[2][4];
#pragma unroll
        for (int mt = 0; mt < 2; mt++)
#pragma unroll
            for (int nt = 0; nt < 4; nt++) oacc[mt][nt] = (f32x4){0.f, 0.f, 0.f, 0.f};
        float m_r[2] = {-1e30f, -1e30f};
        float l_r[2] = {0.f, 0.f};

        int tmax_w = (q0 + 31) >> 6;
        int ntiles = 2 * qs + 2;

        stage(0, 0);
        __syncthreads();

        for (int t = 0; t < ntiles; t++) {
            int buf = t & 1;
            if (t + 1 < ntiles) stage(buf ^ 1, t + 1);

            if (t <= tmax_w) {
                int kv0 = t << 6;
                f32x4 sacc[2][4];
#pragma unroll
                for (int mt = 0; mt < 2; mt++)
#pragma unroll
                    for (int nt = 0; nt < 4; nt++) sacc[mt][nt] = (f32x4){0.f, 0.f, 0.f, 0.f};
                __builtin_amdgcn_s_setprio(1);
#pragma unroll
                for (int nt = 0; nt < 4; nt++) {
                    int rr = nt * 16 + ln;
#pragma unroll
                    for (int kc = 0; kc < 2; kc++) {
                        int unit = (kc * 4 + kq) ^ (rr & 7);
                        bf16x8 bk = *reinterpret_cast<const bf16x8*>(&Kt[buf][rr * 64 + unit * 8]);
#pragma unroll
                        for (int mt = 0; mt < 2; mt++)
                            sacc[mt][nt] = __builtin_amdgcn_mfma_f32_16x16x32_bf16(bk, aq[mt][kc], sacc[mt][nt], 0, 0, 0);
                    }
                }
                __builtin_amdgcn_s_setprio(0);

                if (kv0 + 63 > q0) {
#pragma unroll
                    for (int mt = 0; mt < 2; mt++) {
                        int q = q0 + mt * 16 + ln;
#pragma unroll
                        for (int nt = 0; nt < 4; nt++)
#pragma unroll
                            for (int j = 0; j < 4; j++) {
                                int k = kv0 + (nt >> 1) * 32 + kq * 8 + (nt & 1) * 4 + j;
                                if (k > q) sacc[mt][nt][j] = -1e30f;
                            }
                    }
                }

                float mloc[2];
#pragma unroll
                for (int mt = 0; mt < 2; mt++) {
                    f32x4 m4 = sacc[mt][0];
#pragma unroll
                    for (int nt = 1; nt < 4; nt++) {
                        m4[0] = fmaxf(m4[0], sacc[mt][nt][0]);
                        m4[1] = fmaxf(m4[1], sacc[mt][nt][1]);
                        m4[2] = fmaxf(m4[2], sacc[mt][nt][2]);
                        m4[3] = fmaxf(m4[3], sacc[mt][nt][3]);
                    }
                    mloc[mt] = fmaxf(fmaxf(m4[0], m4[1]), fmaxf(m4[2], m4[3]));
                }
#pragma unroll
                for (int mt = 0; mt < 2; mt++) {
                    mloc[mt] = fmaxf(mloc[mt], __shfl_xor(mloc[mt], 16));
                    mloc[mt] = fmaxf(mloc[mt], __shfl_xor(mloc[mt], 32));
                }

                bool needscale = !__all((mloc[0] <= m_r[0] + 8.0f) && (mloc[1] <= m_r[1] + 8.0f));
                float so[2] = {1.f, 1.f};
                if (needscale) {
#pragma unroll
                    for (int mt = 0; mt < 2; mt++) {
                        float mn = fmaxf(m_r[mt], mloc[mt]);
                        so[mt] = exp2f(m_r[mt] - mn);
                        m_r[mt] = mn;
                    }
                }

                float rs[2] = {0.f, 0.f};
#pragma unroll
                for (int mt = 0; mt < 2; mt++)
#pragma unroll
                    for (int nt = 0; nt < 4; nt++)
#pragma unroll
                        for (int j = 0; j < 4; j++) {
                            float p = exp2f(sacc[mt][nt][j] - m_r[mt]);
                            sacc[mt][nt][j] = p;
                            rs[mt] += p;
                        }
#pragma unroll
                for (int mt = 0; mt < 2; mt++) {
                    rs[mt] += __shfl_xor(rs[mt], 16);
                    rs[mt] += __shfl_xor(rs[mt], 32);
                    l_r[mt] = l_r[mt] * so[mt] + rs[mt];
                }

                if (needscale) {
                    float so_o[2][4];
#pragma unroll
                    for (int mt = 0; mt < 2; mt++)
#pragma unroll
                        for (int j = 0; j < 4; j++)
                            so_o[mt][j] = __shfl(so[mt], kq * 4 + j, 16);
#pragma unroll
                    for (int mt = 0; mt < 2; mt++)
#pragma unroll
                        for (int nt = 0; nt < 4; nt++)
#pragma unroll
                            for (int j = 0; j < 4; j++)
                                oacc[mt][nt][j] *= so_o[mt][j];
                }

                bf16x8 pa[2][2];
#pragma unroll
                for (int mt = 0; mt < 2; mt++)
#pragma unroll
                    for (int kc = 0; kc < 2; kc++) {
                        union { unsigned u[4]; bf16x8 v; } r;
                        r.u[0] = pkbf(sacc[mt][2 * kc][0], sacc[mt][2 * kc][1]);
                        r.u[1] = pkbf(sacc[mt][2 * kc][2], sacc[mt][2 * kc][3]);
                        r.u[2] = pkbf(sacc[mt][2 * kc + 1][0], sacc[mt][2 * kc + 1][1]);
                        r.u[3] = pkbf(sacc[mt][2 * kc + 1][2], sacc[mt][2 * kc + 1][3]);
                        pa[mt][kc] = r.v;
                    }

                __builtin_amdgcn_s_setprio(1);
#pragma unroll
                for (int nt = 0; nt < 4; nt++) {
                    int rr = nt * 16 + ln;
#pragma unroll
                    for (int kc = 0; kc < 2; kc++) {
                        int unit = (kc * 4 + kq) ^ (rr & 7);
                        bf16x8 bv = *reinterpret_cast<const bf16x8*>(&Vt[buf][rr * 64 + unit * 8]);
#pragma unroll
                        for (int mt = 0; mt < 2; mt++)
                            oacc[mt][nt] = __builtin_amdgcn_mfma_f32_16x16x32_bf16(pa[mt][kc], bv, oacc[mt][nt], 0, 0, 0);
                    }
                }
                __builtin_amdgcn_s_setprio(0);
            }
            __syncthreads();
        }

        float lo[2][4];
#pragma unroll
        for (int mt = 0; mt < 2; mt++)
#pragma unroll
            for (int j = 0; j < 4; j++)
                lo[mt][j] = __shfl(l_r[mt], kq * 4 + j, 16);
#pragma unroll
        for (int mt = 0; mt < 2; mt++)
#pragma unroll
            for (int nt = 0; nt < 4; nt++)
#pragma unroll
                for (int j = 0; j < 4; j++) {
                    int row = q0 + mt * 16 + kq * 4 + j;
                    float v = oacc[mt][nt][j] / lo[mt][j];
                    O[((size_t)b * SLEN + row) * DMODEL + h * 64 + nt * 16 + ln] = f2bf(v);
                }
        __syncthreads();
    }
}

// ---- Output projection: out = O @ Wo^T, fp32 result ----
__global__ __launch_bounds__(256) void out_gemm(
    const unsigned short* __restrict__ A, const unsigned short* __restrict__ Wo,
    float* __restrict__ out)
{
    __shared__ alignas(16) unsigned short As[128 * 64];
    __shared__ alignas(16) unsigned short Bs[128 * 64];
    int tid = threadIdx.x, lane = tid & 63, wave = tid >> 6;
    int ln = lane & 15, kq = lane >> 4;
    int wr = wave >> 1, wc = wave & 1;
    int m0 = blockIdx.x * 128;
    int n0 = blockIdx.y * 128;

    f32x4 acc[4][4];
    gemm128_core_sb(A, Wo, m0, n0, tid, acc, As, Bs);

    int m0w = m0 + wr * 64, n0w = n0 + wc * 64;
#pragma unroll
    for (int mt = 0; mt < 4; mt++)
#pragma unroll
        for (int nt = 0; nt < 4; nt++)
#pragma unroll
            for (int j = 0; j < 4; j++) {
                int m = m0w + mt * 16 + kq * 4 + j;
                int n = n0w + nt * 16 + ln;
                out[(size_t)m * DMODEL + n] = acc[mt][nt][j];
            }
}

extern "C" void kernel_launch(void* const* d_in, const int* in_sizes, int n_in,
                              void* d_out, int out_size, void* d_ws, size_t ws_size,
                              hipStream_t stream) {
    const float* x  = (const float*)d_in[0];
    const int* tok  = (const int*)d_in[1];
    const float* wq = (const float*)d_in[2];
    const float* wk = (const float*)d_in[3];
    const float* wv = (const float*)d_in[4];
    const float* wo = (const float*)d_in[5];
    float* out = (float*)d_out;

    const size_t XB_OFF = 0;
    const size_t WQ_OFF = 16777216;
    const size_t WK_OFF = 18874368;
    const size_t WV_OFF = 20971520;
    const size_t WO_OFF = 23068672;
    const size_t Q_OFF  = 25165824;
    const size_t K_OFF  = 41943040;
    const size_t VT_OFF = 58720256;
    const size_t O_OFF  = 75497472;
    const size_t CS_OFF = 92274688;
    const size_t SN_OFF = 92536832;
    const size_t WS_NEEDED = 92798976;
    if (ws_size < WS_NEEDED) return;

    char* ws = (char*)d_ws;
    unsigned short* Xb  = (unsigned short*)(ws + XB_OFF);
    unsigned short* Wqb = (unsigned short*)(ws + WQ_OFF);
    unsigned short* Wkb = (unsigned short*)(ws + WK_OFF);
    unsigned short* Wvb = (unsigned short*)(ws + WV_OFF);
    unsigned short* Wob = (unsigned short*)(ws + WO_OFF);
    unsigned short* Qb  = (unsigned short*)(ws + Q_OFF);
    unsigned short* Kb  = (unsigned short*)(ws + K_OFF);
    unsigned short* VTb = (unsigned short*)(ws + VT_OFF);
    unsigned short* Ob  = (unsigned short*)(ws + O_OFF);
    float* cs_tab = (float*)(ws + CS_OFF);
    float* sn_tab = (float*)(ws + SN_OFF);

    cvt_f32_bf16<<<8192, 256, 0, stream>>>(x, Xb, MROWS * DMODEL);
    cvt_w_all<<<dim3(1024, 4), 256, 0, stream>>>(wq, wk, wv, wo, Wqb, Wkb, Wvb, Wob);
    rope_table<<<256, 256, 0, stream>>>(tok, cs_tab, sn_tab);

    qkv_gemm<<<dim3(MROWS / 128, DMODEL / 64, 1), 256, 0, stream>>>(
        Xb, Wqb, Wkb, Wvb, cs_tab, sn_tab, Qb, Kb, VTb);

    attn_kernel<<<dim3(SLEN / 256, NHEADS, BATCH), 256, 0, stream>>>(Qb, Kb, VTb, Ob);

    out_gemm<<<dim3(MROWS / 128, DMODEL / 128, 1), 256, 0, stream>>>(Ob, Wob, out);
}

// Round 13
// 210.626 us; speedup vs baseline: 1.0512x; 1.0512x over previous
//
#include <hip/hip_runtime.h>

#define BATCH 4
#define SLEN 2048
#define DMODEL 1024
#define NHEADS 16
#define DK 64
#define MROWS (BATCH * SLEN)  // 8192
#define NQB 16                // SLEN/128 q-strips
#define SCALE_LOG2E 0.1803368801111731f  // 0.125 * log2(e), folded into Q

typedef short bf16x8 __attribute__((ext_vector_type(8)));
typedef unsigned short u16x4 __attribute__((ext_vector_type(4)));
typedef float f32x4 __attribute__((ext_vector_type(4)));

__device__ __forceinline__ unsigned short f2bf(float f) {
    unsigned u = __float_as_uint(f);
    unsigned r = u + 0x7FFFu + ((u >> 16) & 1u);
    return (unsigned short)(r >> 16);
}

// packed f32x2 -> bf16x2 (single HW instr; no builtin on gfx950)
__device__ __forceinline__ unsigned pkbf(float a, float b) {
    unsigned r;
    asm volatile("v_cvt_pk_bf16_f32 %0, %1, %2" : "=v"(r) : "v"(a), "v"(b));
    return r;
}

__device__ __forceinline__ void gload_lds16(const void* g, void* l) {
    __builtin_amdgcn_global_load_lds(
        (const __attribute__((address_space(1))) void*)g,
        (__attribute__((address_space(3))) void*)l, 16, 0, 0);
}

__global__ void cvt_f32_bf16(const float* __restrict__ in, unsigned short* __restrict__ out, int n) {
    int i = (blockIdx.x * blockDim.x + threadIdx.x) * 4;
    if (i >= n) return;
    float4 v = *reinterpret_cast<const float4*>(in + i);
    u16x4 o;
    o[0] = f2bf(v.x); o[1] = f2bf(v.y); o[2] = f2bf(v.z); o[3] = f2bf(v.w);
    *reinterpret_cast<u16x4*>(out + i) = o;
}

__global__ void cvt_w_all(const float* __restrict__ w0, const float* __restrict__ w1,
                          const float* __restrict__ w2, const float* __restrict__ w3,
                          unsigned short* __restrict__ o0, unsigned short* __restrict__ o1,
                          unsigned short* __restrict__ o2, unsigned short* __restrict__ o3) {
    int z = blockIdx.y;
    const float* src = (z == 0) ? w0 : (z == 1) ? w1 : (z == 2) ? w2 : w3;
    unsigned short* dst = (z == 0) ? o0 : (z == 1) ? o1 : (z == 2) ? o2 : o3;
    int i = (blockIdx.x * blockDim.x + threadIdx.x) * 4;
    float4 v = *reinterpret_cast<const float4*>(src + i);
    u16x4 o;
    o[0] = f2bf(v.x); o[1] = f2bf(v.y); o[2] = f2bf(v.z); o[3] = f2bf(v.w);
    *reinterpret_cast<u16x4*>(dst + i) = o;
}

__global__ void rope_table(const int* __restrict__ tok, float* __restrict__ cs, float* __restrict__ sn) {
    int idx = blockIdx.x * blockDim.x + threadIdx.x;
    if (idx >= SLEN * 32) return;
    int s = idx >> 5, fi = idx & 31;
    float invf = powf(10000.0f, -(float)(2 * fi) / 64.0f);
    float ang = (float)tok[s] * invf;
    cs[idx] = cosf(ang);
    sn[idx] = sinf(ang);
}

// ======= qkv FUSED (R12-verified, 114.6 us): 128(M) x 64(N) x 3 projections,
// X staged once per K-step, R5 drain semantics. =======
__global__ __launch_bounds__(256) void qkv_gemm(
    const unsigned short* __restrict__ X,
    const unsigned short* __restrict__ Wq,
    const unsigned short* __restrict__ Wk,
    const unsigned short* __restrict__ Wv,
    const float* __restrict__ cs_tab, const float* __restrict__ sn_tab,
    unsigned short* __restrict__ Q, unsigned short* __restrict__ K,
    unsigned short* __restrict__ VT)
{
    __shared__ alignas(16) unsigned short As[128 * 64];      // 16 KB
    __shared__ alignas(16) unsigned short Bs[3][64 * 64];    // 24 KB
    const int tid = threadIdx.x, lane = tid & 63, wave = tid >> 6;
    const int ln = lane & 15, kq = lane >> 4;
    const int wr = wave >> 1, wc = wave & 1;   // wave tile: 64 x 32 (per z)
    const int m0 = blockIdx.x * 128;
    const int n0 = blockIdx.y * 64;
    const unsigned short* Ws[3] = {Wq, Wk, Wv};

    f32x4 acc[3][4][2];
#pragma unroll
    for (int z = 0; z < 3; z++)
#pragma unroll
        for (int a = 0; a < 4; a++)
#pragma unroll
            for (int b = 0; b < 2; b++) acc[z][a][b] = (f32x4){0.f, 0.f, 0.f, 0.f};

    for (int k0 = 0; k0 < DMODEL; k0 += 64) {
        if (k0) __syncthreads();
#pragma unroll
        for (int i = 0; i < 4; i++) {
            int s = i * 256 + tid;
            int r = s >> 3;
            int u = (s & 7) ^ (r & 7);
            gload_lds16(X + (size_t)(m0 + r) * DMODEL + k0 + u * 8, &As[(i * 256 + wave * 64) * 8]);
        }
#pragma unroll
        for (int z = 0; z < 3; z++)
#pragma unroll
            for (int i = 0; i < 2; i++) {
                int s = i * 256 + tid;
                int r = s >> 3;
                int u = (s & 7) ^ (r & 7);
                gload_lds16(Ws[z] + (size_t)(n0 + r) * DMODEL + k0 + u * 8,
                            &Bs[z][(i * 256 + wave * 64) * 8]);
            }
        __syncthreads();

        bf16x8 af[4][2];
#pragma unroll
        for (int mt = 0; mt < 4; mt++) {
            int row = wr * 64 + mt * 16 + ln;
#pragma unroll
            for (int kc = 0; kc < 2; kc++) {
                int u = (kc * 4 + kq) ^ (row & 7);
                af[mt][kc] = *reinterpret_cast<const bf16x8*>(&As[row * 64 + u * 8]);
            }
        }
#pragma unroll
        for (int z = 0; z < 3; z++) {
            bf16x8 bfr[2][2];
#pragma unroll
            for (int nt = 0; nt < 2; nt++) {
                int row = wc * 32 + nt * 16 + ln;
#pragma unroll
                for (int kc = 0; kc < 2; kc++) {
                    int u = (kc * 4 + kq) ^ (row & 7);
                    bfr[nt][kc] = *reinterpret_cast<const bf16x8*>(&Bs[z][row * 64 + u * 8]);
                }
            }
            __builtin_amdgcn_s_setprio(1);
#pragma unroll
            for (int kc = 0; kc < 2; kc++)
#pragma unroll
                for (int mt = 0; mt < 4; mt++)
#pragma unroll
                    for (int nt = 0; nt < 2; nt++)
                        acc[z][mt][nt] = __builtin_amdgcn_mfma_f32_16x16x32_bf16(
                            af[mt][kc], bfr[nt][kc], acc[z][mt][nt], 0, 0, 0);
            __builtin_amdgcn_s_setprio(0);
        }
    }

    int m0w = m0 + wr * 64;
    int n0w = n0 + wc * 32;
#pragma unroll
    for (int z = 0; z < 2; z++) {
        unsigned short* dst = z ? K : Q;
#pragma unroll
        for (int nt = 0; nt < 2; nt++) {
            int n = n0w + nt * 16 + ln;
            int h = n >> 6, d = n & 63;
            int fi = d >> 1;
#pragma unroll
            for (int mt = 0; mt < 4; mt++) {
#pragma unroll
                for (int j = 0; j < 4; j++) {
                    int m = m0w + mt * 16 + kq * 4 + j;
                    int b = m >> 11, s = m & (SLEN - 1);
                    float v = acc[z][mt][nt][j];
                    float c = cs_tab[s * 32 + fi];
                    float si = sn_tab[s * 32 + fi];
                    float p = __shfl_xor(v, 1);
                    v = (d & 1) ? (p * si + v * c) : (v * c - p * si);
                    if (z == 0) v *= SCALE_LOG2E;
                    dst[(((size_t)(b * NHEADS + h) * SLEN + s) << 6) + d] = f2bf(v);
                }
            }
        }
    }
#pragma unroll
    for (int nt = 0; nt < 2; nt++) {
        int n = n0w + nt * 16 + ln;
        int h = n >> 6, d = n & 63;
#pragma unroll
        for (int mt = 0; mt < 4; mt++) {
#pragma unroll
            for (int j = 0; j < 4; j++) {
                int m = m0w + mt * 16 + kq * 4 + j;
                int b = m >> 11, s = m & (SLEN - 1);
                VT[((size_t)(b * NHEADS + h) * DK + d) * SLEN + s] = f2bf(acc[2][mt][nt][j]);
            }
        }
    }
}

// ---- single-buffered 128x128 GEMM core (R5-verified, BK=64) ----
__device__ __forceinline__ void gemm128_core_sb(
    const unsigned short* __restrict__ A, const unsigned short* __restrict__ B,
    int m0, int n0, int tid, f32x4 (&acc)[4][4],
    unsigned short* As, unsigned short* Bs)
{
    int lane = tid & 63, wave = tid >> 6;
    int ln = lane & 15, kq = lane >> 4;
    int wr = wave >> 1, wc = wave & 1;
#pragma unroll
    for (int a = 0; a < 4; a++)
#pragma unroll
        for (int b = 0; b < 4; b++) acc[a][b] = (f32x4){0.f, 0.f, 0.f, 0.f};

    for (int k0 = 0; k0 < DMODEL; k0 += 64) {
        if (k0) __syncthreads();
#pragma unroll
        for (int i = 0; i < 4; i++) {
            int s = i * 256 + tid;
            int r = s >> 3;
            int u = (s & 7) ^ (r & 7);
            gload_lds16(A + (size_t)(m0 + r) * DMODEL + k0 + u * 8, &As[(i * 256 + wave * 64) * 8]);
            gload_lds16(B + (size_t)(n0 + r) * DMODEL + k0 + u * 8, &Bs[(i * 256 + wave * 64) * 8]);
        }
        __syncthreads();

        bf16x8 af[4][2], bfr[4][2];
#pragma unroll
        for (int mt = 0; mt < 4; mt++) {
            int row = wr * 64 + mt * 16 + ln;
#pragma unroll
            for (int kc = 0; kc < 2; kc++) {
                int u = (kc * 4 + kq) ^ (row & 7);
                af[mt][kc] = *reinterpret_cast<const bf16x8*>(&As[row * 64 + u * 8]);
            }
        }
#pragma unroll
        for (int nt = 0; nt < 4; nt++) {
            int row = wc * 64 + nt * 16 + ln;
#pragma unroll
            for (int kc = 0; kc < 2; kc++) {
                int u = (kc * 4 + kq) ^ (row & 7);
                bfr[nt][kc] = *reinterpret_cast<const bf16x8*>(&Bs[row * 64 + u * 8]);
            }
        }
        __builtin_amdgcn_s_setprio(1);
#pragma unroll
        for (int kc = 0; kc < 2; kc++)
#pragma unroll
            for (int mt = 0; mt < 4; mt++)
#pragma unroll
                for (int nt = 0; nt < 4; nt++)
                    acc[mt][nt] = __builtin_amdgcn_mfma_f32_16x16x32_bf16(af[mt][kc], bfr[nt][kc], acc[mt][nt], 0, 0, 0);
        __builtin_amdgcn_s_setprio(0);
    }
}

// ======= Causal flash attention v6: single-pass DUAL-STRIP. 8 waves/block,
// each wave owns 16 q-rows of strip A (15-qb) AND 16 of strip B (qb); the
// two strips share each staged KV tile -> 32-2qb iterations instead of 34,
// strip-B staging eliminated, waves/CU doubled. Per-strip logic is the
// verified v5 code at mt=1. =======
__global__ __launch_bounds__(512, 4) void attn_kernel(
    const unsigned short* __restrict__ Q, const unsigned short* __restrict__ K,
    const unsigned short* __restrict__ VT, unsigned short* __restrict__ O)
{
    __shared__ alignas(16) unsigned short Kt[2][4096];
    __shared__ alignas(16) unsigned short Vt[2][4096];

    int tid = threadIdx.x, lane = tid & 63, wave = tid >> 6;  // 8 waves
    int ln = lane & 15, kq = lane >> 4;
    int qb = blockIdx.x;  // 0..7
    int h = blockIdx.y, b = blockIdx.z;
    size_t headoff = ((size_t)b * NHEADS + h) * SLEN * DK;
    const unsigned short* Qh = Q + headoff;
    const unsigned short* Kh = K + headoff;
    const unsigned short* Vh = VT + headoff;  // [64][SLEN]

    // 512 threads stage one 64x64 K tile (pi-permuted) + V tile: 1 load each
    auto stage = [&](int buf, int t) {
        int kv0 = t << 6;
        int s = tid;
        int r = s >> 3;
        int cb = (s & 7) ^ (r & 7);
        int rp = ((r >> 5) << 5) | (((r >> 2) & 3) << 3) | (((r >> 4) & 1) << 2) | (r & 3);
        gload_lds16(Kh + (size_t)(kv0 + rp) * DK + cb * 8, &Kt[buf][(wave * 64) * 8]);
        gload_lds16(Vh + (size_t)r * SLEN + kv0 + cb * 8, &Vt[buf][(wave * 64) * 8]);
    };

    const int q0A = (NQB - 1 - qb) * 128 + wave * 16;
    const int q0B = qb * 128 + wave * 16;
    const int ntA = 2 * (NQB - 1 - qb) + 2;   // 32-2qb  (loop bound; >= ntB)
    const int tmaxA = (q0A + 15) >> 6;
    const int tmaxB = (q0B + 15) >> 6;

    bf16x8 aqA[2], aqB[2];
#pragma unroll
    for (int kc = 0; kc < 2; kc++) {
        aqA[kc] = *reinterpret_cast<const bf16x8*>(Qh + (size_t)(q0A + ln) * DK + kc * 32 + kq * 8);
        aqB[kc] = *reinterpret_cast<const bf16x8*>(Qh + (size_t)(q0B + ln) * DK + kc * 32 + kq * 8);
    }

    f32x4 oaccA[4], oaccB[4];
#pragma unroll
    for (int nt = 0; nt < 4; nt++) {
        oaccA[nt] = (f32x4){0.f, 0.f, 0.f, 0.f};
        oaccB[nt] = (f32x4){0.f, 0.f, 0.f, 0.f};
    }
    float mA = -1e30f, lA = 0.f, mB = -1e30f, lB = 0.f;

    stage(0, 0);
    __syncthreads();

    for (int t = 0; t < ntA; t++) {
        int buf = t & 1;
        if (t + 1 < ntA) stage(buf ^ 1, t + 1);
        int kv0 = t << 6;

        // -------- one strip (verified v5 logic at mt=1) --------
        auto strip = [&](int q0, bf16x8 (&aq)[2], f32x4 (&oacc)[4], float& m_r, float& l_r) {
            f32x4 sacc[4];
#pragma unroll
            for (int nt = 0; nt < 4; nt++) sacc[nt] = (f32x4){0.f, 0.f, 0.f, 0.f};
            __builtin_amdgcn_s_setprio(1);
#pragma unroll
            for (int nt = 0; nt < 4; nt++) {
                int rr = nt * 16 + ln;
#pragma unroll
                for (int kc = 0; kc < 2; kc++) {
                    int unit = (kc * 4 + kq) ^ (rr & 7);
                    bf16x8 bk = *reinterpret_cast<const bf16x8*>(&Kt[buf][rr * 64 + unit * 8]);
                    sacc[nt] = __builtin_amdgcn_mfma_f32_16x16x32_bf16(bk, aq[kc], sacc[nt], 0, 0, 0);
                }
            }
            __builtin_amdgcn_s_setprio(0);

            if (kv0 + 63 > q0) {
                int q = q0 + ln;
#pragma unroll
                for (int nt = 0; nt < 4; nt++)
#pragma unroll
                    for (int j = 0; j < 4; j++) {
                        int k = kv0 + (nt >> 1) * 32 + kq * 8 + (nt & 1) * 4 + j;
                        if (k > q) sacc[nt][j] = -1e30f;
                    }
            }

            f32x4 m4 = sacc[0];
#pragma unroll
            for (int nt = 1; nt < 4; nt++) {
                m4[0] = fmaxf(m4[0], sacc[nt][0]);
                m4[1] = fmaxf(m4[1], sacc[nt][1]);
                m4[2] = fmaxf(m4[2], sacc[nt][2]);
                m4[3] = fmaxf(m4[3], sacc[nt][3]);
            }
            float mloc = fmaxf(fmaxf(m4[0], m4[1]), fmaxf(m4[2], m4[3]));
            mloc = fmaxf(mloc, __shfl_xor(mloc, 16));
            mloc = fmaxf(mloc, __shfl_xor(mloc, 32));

            bool needscale = !__all(mloc <= m_r + 8.0f);
            float so = 1.f;
            if (needscale) {
                float mn = fmaxf(m_r, mloc);
                so = exp2f(m_r - mn);
                m_r = mn;
            }

            float rs = 0.f;
#pragma unroll
            for (int nt = 0; nt < 4; nt++)
#pragma unroll
                for (int j = 0; j < 4; j++) {
                    float p = exp2f(sacc[nt][j] - m_r);
                    sacc[nt][j] = p;
                    rs += p;
                }
            rs += __shfl_xor(rs, 16);
            rs += __shfl_xor(rs, 32);
            l_r = l_r * so + rs;

            if (needscale) {
                float so_o[4];
#pragma unroll
                for (int j = 0; j < 4; j++) so_o[j] = __shfl(so, kq * 4 + j, 16);
#pragma unroll
                for (int nt = 0; nt < 4; nt++)
#pragma unroll
                    for (int j = 0; j < 4; j++)
                        oacc[nt][j] *= so_o[j];
            }

            bf16x8 pa[2];
#pragma unroll
            for (int kc = 0; kc < 2; kc++) {
                union { unsigned u[4]; bf16x8 v; } r;
                r.u[0] = pkbf(sacc[2 * kc][0], sacc[2 * kc][1]);
                r.u[1] = pkbf(sacc[2 * kc][2], sacc[2 * kc][3]);
                r.u[2] = pkbf(sacc[2 * kc + 1][0], sacc[2 * kc + 1][1]);
                r.u[3] = pkbf(sacc[2 * kc + 1][2], sacc[2 * kc + 1][3]);
                pa[kc] = r.v;
            }

            __builtin_amdgcn_s_setprio(1);
#pragma unroll
            for (int nt = 0; nt < 4; nt++) {
                int rr = nt * 16 + ln;
#pragma unroll
                for (int kc = 0; kc < 2; kc++) {
                    int unit = (kc * 4 + kq) ^ (rr & 7);
                    bf16x8 bv = *reinterpret_cast<const bf16x8*>(&Vt[buf][rr * 64 + unit * 8]);
                    oacc[nt] = __builtin_amdgcn_mfma_f32_16x16x32_bf16(pa[kc], bv, oacc[nt], 0, 0, 0);
                }
            }
            __builtin_amdgcn_s_setprio(0);
        };

        if (t <= tmaxA) strip(q0A, aqA, oaccA, mA, lA);
        if (t <= tmaxB) strip(q0B, aqB, oaccB, mB, lB);

        __syncthreads();
    }

    // ---- epilogue: both strips ----
    {
        float lo[4];
#pragma unroll
        for (int j = 0; j < 4; j++) lo[j] = __shfl(lA, kq * 4 + j, 16);
#pragma unroll
        for (int nt = 0; nt < 4; nt++)
#pragma unroll
            for (int j = 0; j < 4; j++) {
                int row = q0A + kq * 4 + j;
                O[((size_t)b * SLEN + row) * DMODEL + h * 64 + nt * 16 + ln] = f2bf(oaccA[nt][j] / lo[j]);
            }
    }
    {
        float lo[4];
#pragma unroll
        for (int j = 0; j < 4; j++) lo[j] = __shfl(lB, kq * 4 + j, 16);
#pragma unroll
        for (int nt = 0; nt < 4; nt++)
#pragma unroll
            for (int j = 0; j < 4; j++) {
                int row = q0B + kq * 4 + j;
                O[((size_t)b * SLEN + row) * DMODEL + h * 64 + nt * 16 + ln] = f2bf(oaccB[nt][j] / lo[j]);
            }
    }
}

// ---- Output projection: out = O @ Wo^T, fp32 result ----
__global__ __launch_bounds__(256) void out_gemm(
    const unsigned short* __restrict__ A, const unsigned short* __restrict__ Wo,
    float* __restrict__ out)
{
    __shared__ alignas(16) unsigned short As[128 * 64];
    __shared__ alignas(16) unsigned short Bs[128 * 64];
    int tid = threadIdx.x, lane = tid & 63, wave = tid >> 6;
    int ln = lane & 15, kq = lane >> 4;
    int wr = wave >> 1, wc = wave & 1;
    int m0 = blockIdx.x * 128;
    int n0 = blockIdx.y * 128;

    f32x4 acc[4][4];
    gemm128_core_sb(A, Wo, m0, n0, tid, acc, As, Bs);

    int m0w = m0 + wr * 64, n0w = n0 + wc * 64;
#pragma unroll
    for (int mt = 0; mt < 4; mt++)
#pragma unroll
        for (int nt = 0; nt < 4; nt++)
#pragma unroll
            for (int j = 0; j < 4; j++) {
                int m = m0w + mt * 16 + kq * 4 + j;
                int n = n0w + nt * 16 + ln;
                out[(size_t)m * DMODEL + n] = acc[mt][nt][j];
            }
}

extern "C" void kernel_launch(void* const* d_in, const int* in_sizes, int n_in,
                              void* d_out, int out_size, void* d_ws, size_t ws_size,
                              hipStream_t stream) {
    const float* x  = (const float*)d_in[0];
    const int* tok  = (const int*)d_in[1];
    const float* wq = (const float*)d_in[2];
    const float* wk = (const float*)d_in[3];
    const float* wv = (const float*)d_in[4];
    const float* wo = (const float*)d_in[5];
    float* out = (float*)d_out;

    const size_t XB_OFF = 0;
    const size_t WQ_OFF = 16777216;
    const size_t WK_OFF = 18874368;
    const size_t WV_OFF = 20971520;
    const size_t WO_OFF = 23068672;
    const size_t Q_OFF  = 25165824;
    const size_t K_OFF  = 41943040;
    const size_t VT_OFF = 58720256;
    const size_t O_OFF  = 75497472;
    const size_t CS_OFF = 92274688;
    const size_t SN_OFF = 92536832;
    const size_t WS_NEEDED = 92798976;
    if (ws_size < WS_NEEDED) return;

    char* ws = (char*)d_ws;
    unsigned short* Xb  = (unsigned short*)(ws + XB_OFF);
    unsigned short* Wqb = (unsigned short*)(ws + WQ_OFF);
    unsigned short* Wkb = (unsigned short*)(ws + WK_OFF);
    unsigned short* Wvb = (unsigned short*)(ws + WV_OFF);
    unsigned short* Wob = (unsigned short*)(ws + WO_OFF);
    unsigned short* Qb  = (unsigned short*)(ws + Q_OFF);
    unsigned short* Kb  = (unsigned short*)(ws + K_OFF);
    unsigned short* VTb = (unsigned short*)(ws + VT_OFF);
    unsigned short* Ob  = (unsigned short*)(ws + O_OFF);
    float* cs_tab = (float*)(ws + CS_OFF);
    float* sn_tab = (float*)(ws + SN_OFF);

    cvt_f32_bf16<<<8192, 256, 0, stream>>>(x, Xb, MROWS * DMODEL);
    cvt_w_all<<<dim3(1024, 4), 256, 0, stream>>>(wq, wk, wv, wo, Wqb, Wkb, Wvb, Wob);
    rope_table<<<256, 256, 0, stream>>>(tok, cs_tab, sn_tab);

    qkv_gemm<<<dim3(MROWS / 128, DMODEL / 64, 1), 256, 0, stream>>>(
        Xb, Wqb, Wkb, Wvb, cs_tab, sn_tab, Qb, Kb, VTb);

    attn_kernel<<<dim3(SLEN / 256, NHEADS, BATCH), 512, 0, stream>>>(Qb, Kb, VTb, Ob);

    out_gemm<<<dim3(MROWS / 128, DMODEL / 128, 1), 256, 0, stream>>>(Ob, Wob, out);
}